// Round 21
// baseline (518.879 us; speedup 1.0000x reference)
//
#include <hip/hip_runtime.h>
#include <hip/hip_bf16.h>
#include <math.h>

#define NH 8
#define DH 32
#define DIM 256
#define SEQ 2048
#define BATCH 4
#define NB 512            // SEQ / C
#define QKS 512           // q|k packed f32 row stride
#define VGS 320           // v|g packed bf16 row stride: 256 v | 24 g | 40 pad
#define SCALE 0.17677669529663687f  // DH^-0.5

typedef short short8v __attribute__((ext_vector_type(8)));
typedef float float4v __attribute__((ext_vector_type(4)));

__device__ __forceinline__ float sigmoidf_(float x){ return 1.f/(1.f+__expf(-x)); }
__device__ __forceinline__ ushort f2bf(float f){
  uint b = __float_as_uint(f);
  return (ushort)((b + 0x7fffu + ((b>>16)&1u)) >> 16);   // RNE
}
__device__ __forceinline__ float bf2f(ushort u){ return __uint_as_float(((uint)u)<<16); }
__device__ __forceinline__ float bflo(uint u){ return __uint_as_float(u<<16); }
__device__ __forceinline__ float bfhi(uint u){ return __uint_as_float(u & 0xffff0000u); }
__device__ __forceinline__ uint pk2(float a, float b){ return (uint)f2bf(a) | ((uint)f2bf(b)<<16); }
__device__ __forceinline__ void bfu2_to_f32(uint2 u, float* f){
  f[0]=bflo(u.x); f[1]=bfhi(u.x);
  f[2]=bflo(u.y); f[3]=bfhi(u.y);
}

// ---------------- copy (residual stream init) ----------------
__global__ void copy_f32(const float* __restrict__ in, float* __restrict__ out, int n4){
  int i = blockIdx.x*blockDim.x + threadIdx.x;
  if (i < n4) ((float4*)out)[i] = ((const float4*)in)[i];
}

// ---------------- weight packers ----------------
__global__ void build_wqk(const float* __restrict__ Wq, const float* __restrict__ Wk, float* __restrict__ out){
  int i = blockIdx.x*256 + threadIdx.x;          // 4*256*512
  if (i >= 4*256*QKS) return;
  int col = i & 511, rk = (i>>9)&255, l = i>>17;
  out[i] = (col < 256) ? Wq[((size_t)l*256+rk)*256+col] : Wk[((size_t)l*256+rk)*256+col-256];
}
__global__ void build_wvgT(const float* __restrict__ Wv, const float* __restrict__ Wg, ushort* __restrict__ out){
  int i = blockIdx.x*256 + threadIdx.x;          // 4*320*256 : out[l][n][k] = B[k][n]
  if (i >= 4*VGS*256) return;
  int k = i & 255, n = (i>>8)%VGS, l = i/(VGS*256);
  float v = 0.f;
  if      (n < 256) v = Wv[((size_t)l*256+k)*256+n];
  else if (n < 280) v = Wg[((size_t)l*256+k)*24 + (n-256)];
  out[i] = f2bf(v);
}
__global__ void build_wT(const float* __restrict__ in, ushort* __restrict__ out, int L, int K, int N){
  int i = blockIdx.x*256 + threadIdx.x;          // out[l][n][k] = in[l][k][n]
  if (i >= L*K*N) return;
  int k = i % K, n = (i/K) % N, l = i/(K*N);
  out[i] = f2bf(in[((size_t)l*K+k)*N+n]);
}

// ---------------- layernorm: one wave per row, dual f32+bf16 output ----------------
__global__ __launch_bounds__(256) void ln_k(const float* __restrict__ x, const float* __restrict__ g,
                                            const float* __restrict__ b, float* __restrict__ h,
                                            ushort* __restrict__ hb){
  int row  = blockIdx.x*4 + (threadIdx.x>>6);
  int lane = threadIdx.x & 63;
  int c = lane*4;
  const float* xr = x + (size_t)row*DIM + c;
  float4 v = *(const float4*)xr;
  float s = v.x+v.y+v.z+v.w;
  float q = v.x*v.x+v.y*v.y+v.z*v.z+v.w*v.w;
  #pragma unroll
  for (int off=32; off>0; off>>=1){ s += __shfl_xor(s, off); q += __shfl_xor(q, off); }
  float mean = s * (1.f/DIM);
  float var  = q * (1.f/DIM) - mean*mean;
  float rs = rsqrtf(var + 1e-5f);
  float4 gg = *(const float4*)(g + c);
  float4 bb = *(const float4*)(b + c);
  float4 o;
  o.x = (v.x-mean)*rs*gg.x + bb.x;
  o.y = (v.y-mean)*rs*gg.y + bb.y;
  o.z = (v.z-mean)*rs*gg.z + bb.z;
  o.w = (v.w-mean)*rs*gg.w + bb.w;
  *(float4*)(h + (size_t)row*DIM + c) = o;
  uint2 u;
  u.x = pk2(o.x, o.y);
  u.y = pk2(o.z, o.w);
  *(uint2*)&hb[(size_t)row*DIM + c] = u;
}

// ---------------- fused projection: qk f32 GEMM + vg bf16 MFMA GEMM + pooling ----------------
__global__ __launch_bounds__(256) void gemm_qkvg(
    const float* __restrict__ hA, const ushort* __restrict__ hbA,
    const float* __restrict__ Bqk, const ushort* __restrict__ BvgT,
    float* __restrict__ qkb, ushort* __restrict__ vgu,
    float* __restrict__ kcb, ushort* __restrict__ vctb){
  __shared__ __align__(16) char smem[25600];
  int tid = threadIdx.x;
  int m0 = blockIdx.x*128;
  if (blockIdx.y < 8){
    // ---------- f32 path (qk), tile 128x64, BK=32, 8x4/thread ----------
    float (*As)[132] = (float(*)[132])smem;
    float (*Bs)[68]  = (float(*)[68])(smem + 16896);
    int n0 = blockIdx.y*64;
    int tx = tid & 15, tyy = tid >> 4;
    int ar = tid >> 1;
    int ac = (tid & 1)*16;
    int bk = tid >> 3;
    int bn = (tid & 7)*8;
    const float* Ap = hA + (size_t)(m0+ar)*256 + ac;
    const float* Bp = Bqk + (size_t)bk*QKS + n0 + bn;
    float4 apre[4], bpre[2];
    #pragma unroll
    for (int j=0;j<4;j++) apre[j] = *(const float4*)(Ap + 4*j);
    bpre[0] = *(const float4*)Bp;
    bpre[1] = *(const float4*)(Bp + 4);
    float acc[8][4];
    #pragma unroll
    for (int i=0;i<8;i++)
      #pragma unroll
      for (int j=0;j<4;j++) acc[i][j]=0.f;
    for (int k0=0; k0<256; k0+=32){
      #pragma unroll
      for (int j=0;j<4;j++){
        As[ac+4*j+0][ar]=apre[j].x; As[ac+4*j+1][ar]=apre[j].y;
        As[ac+4*j+2][ar]=apre[j].z; As[ac+4*j+3][ar]=apre[j].w;
      }
      *(float4*)&Bs[bk][bn]   = bpre[0];
      *(float4*)&Bs[bk][bn+4] = bpre[1];
      __syncthreads();
      if (k0 + 32 < 256){
        #pragma unroll
        for (int j=0;j<4;j++) apre[j] = *(const float4*)(Ap + k0 + 32 + 4*j);
        bpre[0] = *(const float4*)(Bp + (size_t)(k0+32)*QKS);
        bpre[1] = *(const float4*)(Bp + (size_t)(k0+32)*QKS + 4);
      }
      #pragma unroll
      for (int kk=0;kk<32;kk++){
        float4 bv  = *(const float4*)&Bs[kk][tx*4];
        float4 av0 = *(const float4*)&As[kk][tyy*8];
        float4 av1 = *(const float4*)&As[kk][tyy*8+4];
        float av[8] = {av0.x,av0.y,av0.z,av0.w,av1.x,av1.y,av1.z,av1.w};
        float bw[4] = {bv.x,bv.y,bv.z,bv.w};
        #pragma unroll
        for (int i=0;i<8;i++)
          #pragma unroll
          for (int j=0;j<4;j++) acc[i][j] += av[i]*bw[j];
      }
      __syncthreads();
    }
    #pragma unroll
    for (int i=0;i<8;i++){
      int m = m0 + tyy*8 + i;
      #pragma unroll
      for (int j=0;j<4;j++)
        qkb[(size_t)m*QKS + n0 + tx*4 + j] = acc[i][j];
    }
    if (n0 >= 256){   // kc pooling: same add order/values as original pool_k
      #pragma unroll
      for (int G=0; G<2; ++G){
        int row = m0 + tyy*8 + 4*G;
        int bi = row >> 11;
        int np = (row & 2047) >> 2;
        #pragma unroll
        for (int j=0;j<4;j++){
          int col = n0 + tx*4 + j - 256;
          int h_ = col >> 5, d = col & 31;
          float pv = 0.25f*(((acc[4*G][j] + acc[4*G+1][j]) + acc[4*G+2][j]) + acc[4*G+3][j]);
          kcb[(((size_t)(bi*NH + h_))*NB + np)*DH + d] = pv;
        }
      }
    }
  } else {
    // ---------- bf16 MFMA path (vg), tile 128x64, BK=64 ----------
    ushort* Al = (ushort*)smem;
    ushort* Bl = (ushort*)(smem + 16384);
    int n0 = (blockIdx.y - 8)*64;
    int w = tid>>6, lane = tid&63;
    int wm = w>>1, wn = w&1;
    float4v acc[4][2];
    #pragma unroll
    for (int i=0;i<4;i++)
      #pragma unroll
      for (int j=0;j<2;j++) acc[i][j] = (float4v){0.f,0.f,0.f,0.f};
    for (int k0=0; k0<256; k0+=64){
      #pragma unroll
      for (int i=0;i<4;i++){
        int id = tid + 256*i;
        int r = id>>3, c = id&7;
        *(uint4*)&Al[r*64 + ((c ^ (r&7))*8)] = *(const uint4*)&hbA[(size_t)(m0+r)*256 + k0 + c*8];
      }
      #pragma unroll
      for (int i=0;i<2;i++){
        int id = tid + 256*i;
        int r = id>>3, c = id&7;
        *(uint4*)&Bl[r*64 + ((c ^ (r&7))*8)] = *(const uint4*)&BvgT[(size_t)(n0+r)*256 + k0 + c*8];
      }
      __syncthreads();
      #pragma unroll
      for (int kk=0; kk<2; ++kk){
        short8v a[4], bfr[2];
        #pragma unroll
        for (int mf=0; mf<4; mf++){
          int r = wm*64 + mf*16 + (lane&15);
          int c = (kk*4 + (lane>>4)) ^ (r&7);
          a[mf] = *(short8v*)&Al[r*64 + c*8];
        }
        #pragma unroll
        for (int nf=0; nf<2; nf++){
          int r = wn*32 + nf*16 + (lane&15);
          int c = (kk*4 + (lane>>4)) ^ (r&7);
          bfr[nf] = *(short8v*)&Bl[r*64 + c*8];
        }
        #pragma unroll
        for (int mf=0; mf<4; mf++)
          #pragma unroll
          for (int nf=0; nf<2; nf++)
            acc[mf][nf] = __builtin_amdgcn_mfma_f32_16x16x32_bf16(a[mf], bfr[nf], acc[mf][nf], 0, 0, 0);
      }
      __syncthreads();
    }
    #pragma unroll
    for (int nf=0; nf<2; nf++){
      int col = n0 + wn*32 + nf*16 + (lane&15);
      #pragma unroll
      for (int mf=0; mf<4; mf++){
        ushort s4[4];
        #pragma unroll
        for (int r=0; r<4; r++){
          int row = m0 + wm*64 + mf*16 + (lane>>4)*4 + r;
          s4[r] = f2bf(acc[mf][nf][r]);
          vgu[(size_t)row*VGS + col] = s4[r];
        }
        if (col < 256){   // vct pooling: bf16 round -> sequential mean (matches pool_k)
          int row0 = m0 + wm*64 + mf*16 + (lane>>4)*4;
          int bi = row0 >> 11;
          int np = (row0 & 2047) >> 2;
          float pv = 0.25f*(((bf2f(s4[0]) + bf2f(s4[1])) + bf2f(s4[2])) + bf2f(s4[3]));
          int h_ = col >> 5, d = col & 31;
          vctb[(((size_t)(bi*NH + h_))*DH + d)*NB + np] = f2bf(pv);
        }
      }
    }
  }
}

// ---------------- bf16 MFMA GEMM: tile 128x64 ----------------
template<bool BIAS, bool LEAKY, bool ACC, bool OBF16>
__global__ __launch_bounds__(256) void gemm_bf16(const ushort* __restrict__ A, const ushort* __restrict__ Bt,
                                                 const float* __restrict__ bias, void* __restrict__ Cv,
                                                 int M, int N, int K){
  __shared__ ushort Al[128*64];
  __shared__ ushort Bl[64*64];
  int tid = threadIdx.x;
  int m0 = blockIdx.x*128, n0 = blockIdx.y*64;
  int w = tid>>6, lane = tid&63;
  int wm = w>>1, wn = w&1;
  float4v acc[4][2];
  #pragma unroll
  for (int i=0;i<4;i++)
    #pragma unroll
    for (int j=0;j<2;j++) acc[i][j] = (float4v){0.f,0.f,0.f,0.f};
  for (int k0=0; k0<K; k0+=64){
    #pragma unroll
    for (int i=0;i<4;i++){
      int id = tid + 256*i;
      int r = id>>3, c = id&7;
      *(uint4*)&Al[r*64 + ((c ^ (r&7))*8)] = *(const uint4*)&A[(size_t)(m0+r)*K + k0 + c*8];
    }
    #pragma unroll
    for (int i=0;i<2;i++){
      int id = tid + 256*i;
      int r = id>>3, c = id&7;
      *(uint4*)&Bl[r*64 + ((c ^ (r&7))*8)] = *(const uint4*)&Bt[(size_t)(n0+r)*K + k0 + c*8];
    }
    __syncthreads();
    #pragma unroll
    for (int kk=0; kk<2; ++kk){
      short8v a[4], bfr[2];
      #pragma unroll
      for (int mf=0; mf<4; mf++){
        int r = wm*64 + mf*16 + (lane&15);
        int c = (kk*4 + (lane>>4)) ^ (r&7);
        a[mf] = *(short8v*)&Al[r*64 + c*8];
      }
      #pragma unroll
      for (int nf=0; nf<2; nf++){
        int r = wn*32 + nf*16 + (lane&15);
        int c = (kk*4 + (lane>>4)) ^ (r&7);
        bfr[nf] = *(short8v*)&Bl[r*64 + c*8];
      }
      #pragma unroll
      for (int mf=0; mf<4; mf++)
        #pragma unroll
        for (int nf=0; nf<2; nf++)
          acc[mf][nf] = __builtin_amdgcn_mfma_f32_16x16x32_bf16(a[mf], bfr[nf], acc[mf][nf], 0, 0, 0);
    }
    __syncthreads();
  }
  #pragma unroll
  for (int nf=0; nf<2; nf++){
    int col = n0 + wn*32 + nf*16 + (lane&15);
    float bv = BIAS ? bias[col] : 0.f;
    #pragma unroll
    for (int mf=0; mf<4; mf++){
      #pragma unroll
      for (int r=0; r<4; r++){
        int row = m0 + wm*64 + mf*16 + (lane>>4)*4 + r;
        float vv = acc[mf][nf][r];
        if (BIAS) vv += bv;
        if (LEAKY) vv = vv > 0.f ? vv : 0.01f*vv;
        if (OBF16) ((ushort*)Cv)[(size_t)row*N + col] = f2bf(vv);
        else {
          float* C = (float*)Cv;
          if (ACC) vv += C[(size_t)row*N + col];
          C[(size_t)row*N + col] = vv;
        }
      }
    }
  }
}

// ---------------- bf16 MFMA GEMM: tile 64x64 (2x grid for N=256 GEMMs) ----------------
// Same loader swizzle / C layout as gemm_bf16; wave w owns output rows [16w,16w+16).
template<bool BIAS, bool LEAKY, bool ACC, bool OBF16>
__global__ __launch_bounds__(256) void gemm_bf16_64(const ushort* __restrict__ A, const ushort* __restrict__ Bt,
                                                    const float* __restrict__ bias, void* __restrict__ Cv,
                                                    int M, int N, int K){
  __shared__ ushort Al[64*64];
  __shared__ ushort Bl[64*64];
  int tid = threadIdx.x;
  int m0 = blockIdx.x*64, n0 = blockIdx.y*64;
  int w = tid>>6, lane = tid&63;
  float4v acc[4];
  #pragma unroll
  for (int j=0;j<4;j++) acc[j] = (float4v){0.f,0.f,0.f,0.f};
  for (int k0=0; k0<K; k0+=64){
    #pragma unroll
    for (int i=0;i<2;i++){
      int id = tid + 256*i;
      int r = id>>3, c = id&7;
      *(uint4*)&Al[r*64 + ((c ^ (r&7))*8)] = *(const uint4*)&A[(size_t)(m0+r)*K + k0 + c*8];
      *(uint4*)&Bl[r*64 + ((c ^ (r&7))*8)] = *(const uint4*)&Bt[(size_t)(n0+r)*K + k0 + c*8];
    }
    __syncthreads();
    #pragma unroll
    for (int kk=0; kk<2; ++kk){
      int ra = 16*w + (lane&15);
      int ca = (kk*4 + (lane>>4)) ^ (ra&7);
      short8v a = *(short8v*)&Al[ra*64 + ca*8];
      #pragma unroll
      for (int nf=0; nf<4; nf++){
        int rb = nf*16 + (lane&15);
        int cb = (kk*4 + (lane>>4)) ^ (rb&7);
        short8v bfr = *(short8v*)&Bl[rb*64 + cb*8];
        acc[nf] = __builtin_amdgcn_mfma_f32_16x16x32_bf16(a, bfr, acc[nf], 0, 0, 0);
      }
    }
    __syncthreads();
  }
  #pragma unroll
  for (int nf=0; nf<4; nf++){
    int col = n0 + nf*16 + (lane&15);
    float bv = BIAS ? bias[col] : 0.f;
    #pragma unroll
    for (int r=0; r<4; r++){
      int row = m0 + 16*w + (lane>>4)*4 + r;
      float vv = acc[nf][r];
      if (BIAS) vv += bv;
      if (LEAKY) vv = vv > 0.f ? vv : 0.01f*vv;
      if (OBF16) ((ushort*)Cv)[(size_t)row*N + col] = f2bf(vv);
      else {
        float* C = (float*)Cv;
        if (ACC) vv += C[(size_t)row*N + col];
        C[(size_t)row*N + col] = vv;
      }
    }
  }
}

// ---------------- fused NSA attention v13: swapped-operand MFMA, reg-direct phase 2 ----------------
// 32 groups x 64 tokens per (b,h). Grid 1024, 4 waves.
// Block e: hh=e&7 (XCD slot), b=(e>>3)&3, q=(e>>5)&7, r=e>>8;
//   g = {31-q, q, 23-q, 8+q}[r] -> bijective, per-CU weight ~constant, heavy first.
// Phase 1 per 64-n tile: stage kt f32 + vcT bf16 [d][n]; wave w scores rows
//   [16w,16w+16) (lane=token, EXACT grouped-4 f32 dot -> argmax bit-preserved),
//   p->bf16 into Pl at identity k-offsets. MFMA swapped (validated in R17):
//   A=vcT (rows=d), B=Pl rows [16w,16w+16) -> lane owns token w*16+(lane&15),
//   d-set {4m..4m+3}u{16+4m..} (m=lane>>4); oc stays IN REGISTERS (ocl deleted:
//   LDS 35.3->25.6KB -> 6 blocks/CU capacity for tail backfill).
// Phase 2 (all 4 waves, 16 tokens each): R17's validated body, 4 meta splits.
__global__ __launch_bounds__(256, 4) void nsa_attn(
    const float* __restrict__ qk, const ushort* __restrict__ vg,
    const float* __restrict__ kc, const ushort* __restrict__ vct,
    ushort* __restrict__ o)
{
  __shared__ float  kt[64*32];       // 8 KB f32 kc tile
  __shared__ ushort vcT[32*72];      // 4.5 KB bf16 Vc^T tile [d][n], pad 8
  __shared__ ushort Pl[64*72];       // 9 KB bf16 P tile [tok][n], pad 8
  __shared__ float4 meta[4*64];      // 4 KB (l, best, bestn, -)   -> 25.6 KB
  int e = blockIdx.x;
  int hh = e & 7;
  int b  = (e >> 3) & 3;
  int qq = (e >> 5) & 7;
  int r  = e >> 8;
  int g  = (r==0) ? (31-qq) : (r==1) ? qq : (r==2) ? (23-qq) : (8+qq);
  int tid = threadIdx.x;
  int w = tid >> 6, lane = tid & 63;
  const float*  kcg  = kc  + ((size_t)(b*NH + hh)*NB)*DH;
  const ushort* vctg = vct + ((size_t)(b*NH + hh)*DH)*NB;

  float4v acc0 = (float4v){0.f,0.f,0.f,0.f};
  float4v acc1 = (float4v){0.f,0.f,0.f,0.f};

  // ---- phase 1
  {
    int t = g*64 + lane;
    int own = t >> 2, nvis = (t+1) >> 2;
    int nmax = 16*(g+1);                  // block-uniform visibility bound
    float qv[32];
    {
      const float4* qr = (const float4*)(qk + ((size_t)b*SEQ + t)*QKS + hh*DH);
      #pragma unroll
      for (int d8=0; d8<8; d8++){
        float4 a4 = qr[d8];
        qv[4*d8]=a4.x; qv[4*d8+1]=a4.y; qv[4*d8+2]=a4.z; qv[4*d8+3]=a4.w;
      }
    }
    float l = 0.f, best = -1e30f;
    int bn1 = -1;

    int tiles = (g + 4) >> 2;             // ceil(16(g+1)/64)
    for (int ti=0; ti<tiles; ++ti){
      int base = ti*64;
      if (ti) __syncthreads();            // prev tile's MFMA reads done
      {                                   // stage kt (2 float4/thr) + vcT (1 uint4/thr, [d][n])
        const float4* sk = (const float4*)(kcg + (size_t)base*DH);
        ((float4*)kt)[tid]     = sk[tid];
        ((float4*)kt)[tid+256] = sk[tid+256];
        int sd = tid >> 3, sn = (tid & 7)*8;
        *(uint4*)&vcT[sd*72 + sn] = *(const uint4*)&vctg[(size_t)sd*NB + base + sn];
      }
      __syncthreads();
      // score phase: wave w owns rows [w*16, w*16+16)
      float ps[16];
      #pragma unroll
      for (int j=0; j<16; ++j){
        int rr = w*16 + j;
        int n = base + rr;
        float p = 0.f;
        if (n < nmax){                    // wave-uniform
          const float4* kp = (const float4*)&kt[rr*32];
          float s = 0.f;
          #pragma unroll
          for (int d8=0; d8<8; d8++){     // exact grouped-4 ordering: argmax-stable
            float4 k4 = kp[d8];
            s += qv[4*d8]*k4.x + qv[4*d8+1]*k4.y + qv[4*d8+2]*k4.z + qv[4*d8+3]*k4.w;
          }
          s *= SCALE;
          bool act = (n < nvis);
          if (act && n != own && s > best){ best = s; bn1 = n; }  // ascending n in-wave
          p = act ? __expf(s) : 0.f;      // max-free: |s| small, exp safe
          l += p;
        }
        ps[j] = p;
      }
      {                                   // P[lane][w*16..+16] as 2x b128 (identity k-map)
        uint4 u0, u1;
        u0.x = pk2(ps[0],ps[1]);  u0.y = pk2(ps[2],ps[3]);
        u0.z = pk2(ps[4],ps[5]);  u0.w = pk2(ps[6],ps[7]);
        u1.x = pk2(ps[8],ps[9]);  u1.y = pk2(ps[10],ps[11]);
        u1.z = pk2(ps[12],ps[13]);u1.w = pk2(ps[14],ps[15]);
        *(uint4*)&Pl[lane*72 + w*16]     = u0;
        *(uint4*)&Pl[lane*72 + w*16 + 8] = u1;
      }
      __syncthreads();                    // P complete
      // MFMA (swapped): A=vcT rows d, B=Pl rows [16w,16w+16), K=64 via 2 ksteps
      #pragma unroll
      for (int ks=0; ks<2; ++ks){
        short8v bfrag = *(short8v*)&Pl [(16*w + (lane&15))*72 + ks*32 + (lane>>4)*8];
        short8v a0    = *(short8v*)&vcT[(lane&15)*72          + ks*32 + (lane>>4)*8];
        short8v a1    = *(short8v*)&vcT[((lane&15)+16)*72     + ks*32 + (lane>>4)*8];
        acc0 = __builtin_amdgcn_mfma_f32_16x16x32_bf16(a0, bfrag, acc0, 0, 0, 0);
        acc1 = __builtin_amdgcn_mfma_f32_16x16x32_bf16(a1, bfrag, acc1, 0, 0, 0);
      }
    }
    meta[w*64 + lane] = make_float4(l, best, __int_as_float(bn1), 0.f);
  }
  __syncthreads();

  // ---- phase 2: token = g*64 + w*16 + (lane&15); lane m=lane>>4 owns
  //      d-set {4m..4m+3} u {16+4m..16+4m+3}; oc comes straight from acc0/acc1.
  {
    int c = lane & 15, m = lane >> 4;
    int tokidx = w*16 + c;
    int t = g*64 + tokidx;
    int own = t >> 2, nvis = (t+1) >> 2;
    int dA = 4*m, dB = 16 + 4*m;
    float q8[8];
    {
      const float* qrow = qk + ((size_t)b*SEQ + t)*QKS + hh*DH;
      float4 a4 = *(const float4*)(qrow + dA);
      float4 b4 = *(const float4*)(qrow + dB);
      q8[0]=a4.x; q8[1]=a4.y; q8[2]=a4.z; q8[3]=a4.w;
      q8[4]=b4.x; q8[5]=b4.y; q8[6]=b4.z; q8[7]=b4.w;
    }
    float out8[8];
    #pragma unroll
    for (int j=0;j<4;j++){ out8[j] = acc0[j]; out8[4+j] = acc1[j]; }
    float ll = 0.f, bb = -1e30f;
    int bn = (own==0) ? 1 : 0;         // jax top_k fallback
    #pragma unroll
    for (int sp=0; sp<4; ++sp){
      float4 m4 = meta[sp*64 + tokidx];
      ll += m4.x;
      int mi = __float_as_int(m4.z);
      // equal scores resolve to the lower n (mi>=0 excludes empty partials)
      if (m4.y > bb || (m4.y == bb && mi >= 0 && mi < bn)){ bb = m4.y; bn = mi; }
    }
    const ushort* gr = vg + ((size_t)b*SEQ + t)*VGS + 256;
    float g0 = sigmoidf_(bf2f(gr[hh])), g1 = sigmoidf_(bf2f(gr[8+hh])), g2 = sigmoidf_(bf2f(gr[16+hh]));
    float inv = (nvis > 0) ? g0/ll : 0.f;
    #pragma unroll
    for (int j=0;j<8;j++) out8[j] *= inv;

    // selection branch: own block + best block, causal token mask, d-split dots
    const float*  kb2 = qk + (size_t)b*SEQ*QKS + 256 + hh*DH;
    const ushort* vb2 = vg + (size_t)b*SEQ*VGS + hh*DH;
    float s2[8];
    float m2 = -1e30f;
    #pragma unroll
    for (int ki=0; ki<8; ++ki){
      int tt = (ki<4 ? own : bn)*4 + (ki&3);
      float s = -1e30f;
      if (tt <= t){                       // uniform across the 4 lanes of this token
        const float* kr = kb2 + (size_t)tt*QKS;
        float4 a4 = *(const float4*)(kr + dA);
        float4 c4 = *(const float4*)(kr + dB);
        float ps = q8[0]*a4.x + q8[1]*a4.y + q8[2]*a4.z + q8[3]*a4.w
                 + q8[4]*c4.x + q8[5]*c4.y + q8[6]*c4.z + q8[7]*c4.w;
        ps += __shfl_xor(ps, 16);
        ps += __shfl_xor(ps, 32);
        s = ps*SCALE;
        m2 = fmaxf(m2, s);
      }
      s2[ki] = s;
    }
    float l2 = 0.f;
    #pragma unroll
    for (int ki=0; ki<8; ++ki)
      if (s2[ki] > -1e29f) l2 += __expf(s2[ki] - m2);
    float inv2 = g1/l2;                   // l2 >= 1 (self token always visible)
    #pragma unroll
    for (int ki=0; ki<8; ++ki){
      int tt = (ki<4 ? own : bn)*4 + (ki&3);
      if (tt <= t){
        float pw = __expf(s2[ki] - m2) * inv2;
        float fA[4], fB[4];
        bfu2_to_f32(*(const uint2*)(vb2 + (size_t)tt*VGS + dA), fA);
        bfu2_to_f32(*(const uint2*)(vb2 + (size_t)tt*VGS + dB), fB);
        #pragma unroll
        for (int j=0;j<4;j++){ out8[j] += pw*fA[j]; out8[4+j] += pw*fB[j]; }
      }
    }

    // sliding window (W=2): tokens t-1, t
    int tp = (t>0) ? t-1 : 0;
    float sa, sb;
    {
      const float* ka = kb2 + (size_t)tp*QKS;
      const float* kb4= kb2 + (size_t)t *QKS;
      float4 a0 = *(const float4*)(ka + dA), a1 = *(const float4*)(ka + dB);
      float4 b0 = *(const float4*)(kb4 + dA), b1 = *(const float4*)(kb4 + dB);
      float pa_ = q8[0]*a0.x + q8[1]*a0.y + q8[2]*a0.z + q8[3]*a0.w
                + q8[4]*a1.x + q8[5]*a1.y + q8[6]*a1.z + q8[7]*a1.w;
      float pb_ = q8[0]*b0.x + q8[1]*b0.y + q8[2]*b0.z + q8[3]*b0.w
                + q8[4]*b1.x + q8[5]*b1.y + q8[6]*b1.z + q8[7]*b1.w;
      pa_ += __shfl_xor(pa_, 16); pa_ += __shfl_xor(pa_, 32);
      pb_ += __shfl_xor(pb_, 16); pb_ += __shfl_xor(pb_, 32);
      sa = pa_*SCALE; sb = pb_*SCALE;
    }
    float m3 = (t>0) ? fmaxf(sa, sb) : sb;
    float pa = (t>0) ? __expf(sa-m3) : 0.f;
    float pb = __expf(sb-m3);
    float inv3 = g2/(pa+pb);
    float va[4], vaB[4], vbv[4], vbB[4];
    bfu2_to_f32(*(const uint2*)(vb2 + (size_t)tp*VGS + dA), va);
    bfu2_to_f32(*(const uint2*)(vb2 + (size_t)tp*VGS + dB), vaB);
    bfu2_to_f32(*(const uint2*)(vb2 + (size_t)t *VGS + dA), vbv);
    bfu2_to_f32(*(const uint2*)(vb2 + (size_t)t *VGS + dB), vbB);
    ushort* orow = o + ((size_t)b*SEQ + t)*DIM + hh*DH;
    float rrA[4], rrB[4];
    #pragma unroll
    for (int j=0;j<4;j++){
      rrA[j] = out8[j]   + (pa*va[j]  + pb*vbv[j])*inv3;
      rrB[j] = out8[4+j] + (pa*vaB[j] + pb*vbB[j])*inv3;
    }
    uint2 uA, uB;
    uA.x = pk2(rrA[0], rrA[1]); uA.y = pk2(rrA[2], rrA[3]);
    uB.x = pk2(rrB[0], rrB[1]); uB.y = pk2(rrB[2], rrB[3]);
    *(uint2*)&orow[dA] = uA;
    *(uint2*)&orow[dB] = uB;
  }
}

extern "C" void kernel_launch(void* const* d_in, const int* in_sizes, int n_in,
                              void* d_out, int out_size, void* d_ws, size_t ws_size,
                              hipStream_t stream) {
  const float* x_in   = (const float*)d_in[0];
  const float* ln_a_g = (const float*)d_in[1];
  const float* ln_a_b = (const float*)d_in[2];
  const float* Wq     = (const float*)d_in[3];
  const float* Wk     = (const float*)d_in[4];
  const float* Wv     = (const float*)d_in[5];
  const float* Wg     = (const float*)d_in[6];
  const float* Wo     = (const float*)d_in[7];
  const float* ln_f_g = (const float*)d_in[8];
  const float* ln_f_b = (const float*)d_in[9];
  const float* W1     = (const float*)d_in[10];
  const float* b1     = (const float*)d_in[11];
  const float* W2     = (const float*)d_in[12];
  const float* b2     = (const float*)d_in[13];

  float* xout = (float*)d_out;             // running residual stream [8192][256] f32
  float* ws = (float*)d_ws;
  const size_t NTOK = (size_t)BATCH*SEQ;   // 8192
  float* h    = ws;                                    // [8192][256] f32
  float* qkb  = h    + NTOK*DIM;                       // [8192][512] f32
  float* kcb  = qkb  + NTOK*QKS;                       // [4][8][512][32] f32
  ushort* vctb = (ushort*)(kcb + (size_t)BATCH*NH*NB*DH);  // [4][8][32][512] bf16 (transposed)
  float* wqk  = (float*)(vctb + (size_t)BATCH*NH*NB*DH);   // [4][256][512] f32
  ushort* hb   = (ushort*)(wqk + (size_t)4*DIM*QKS);   // [8192][256] bf16
  ushort* vgu  = hb   + NTOK*DIM;                      // [8192][320] bf16
  ushort* obu  = vgu  + NTOK*VGS;                      // [8192][256] bf16
  ushort* midu = obu  + NTOK*DIM;                      // [8192][512] bf16
  ushort* wvgT = midu + NTOK*512;                      // [4][320][256] bf16
  ushort* woT  = wvgT + (size_t)4*VGS*DIM;             // [4][256][256] bf16
  ushort* w1T  = woT  + (size_t)4*DIM*DIM;             // [2][512][256] bf16
  ushort* w2T  = w1T  + (size_t)2*512*DIM;             // [2][256][512] bf16

  copy_f32<<<2048, 256, 0, stream>>>(x_in, xout, (int)(NTOK*DIM/4));
  build_wqk <<<(4*256*QKS+255)/256, 256, 0, stream>>>(Wq, Wk, wqk);
  build_wvgT<<<(4*VGS*256+255)/256, 256, 0, stream>>>(Wv, Wg, wvgT);
  build_wT  <<<(4*256*256+255)/256, 256, 0, stream>>>(Wo, woT, 4, 256, 256);
  build_wT  <<<(2*256*512+255)/256, 256, 0, stream>>>(W1, w1T, 2, 256, 512);
  build_wT  <<<(2*512*256+255)/256, 256, 0, stream>>>(W2, w2T, 2, 512, 256);

  dim3 gfused(64,13), g64(128,4), g8(64,8);
  for (int i=0;i<4;i++){
    ln_k<<<2048,256,0,stream>>>(xout, ln_a_g + i*DIM, ln_a_b + i*DIM, h, hb);
    gemm_qkvg<<<gfused,256,0,stream>>>(h, hb, wqk + (size_t)i*DIM*QKS, wvgT + (size_t)i*VGS*DIM,
                                       qkb, vgu, kcb, vctb);
    nsa_attn<<<1024,256,0,stream>>>(qkb, vgu, kcb, vctb, obu);
    gemm_bf16_64<false,false,true,false><<<g64,256,0,stream>>>(obu, woT + (size_t)i*DIM*DIM, nullptr, xout, 8192,DIM,256);
    if (i & 1){
      int l = i >> 1;
      ln_k<<<2048,256,0,stream>>>(xout, ln_f_g + l*DIM, ln_f_b + l*DIM, h, hb);
      gemm_bf16<true,true,false,true><<<g8,256,0,stream>>>(hb,   w1T + (size_t)l*512*DIM, b1 + l*512, midu, 8192,512,256);
      gemm_bf16_64<true,false,true,false><<<g64,256,0,stream>>>(midu, w2T + (size_t)l*DIM*512, b2 + l*DIM, xout, 8192,DIM,512);
    }
  }
}